// Round 1
// baseline (537.282 us; speedup 1.0000x reference)
//
#include <hip/hip_runtime.h>
#include <hip/hip_bf16.h>
#include <stdint.h>

// MoE FFN, top-1 routing. x:[4,2048,1024] f32, experts 8, ffn 1024->4096->1024.
// Strategy: fp64 gating+argmax -> bucket tokens per expert -> bf16 MFMA GEMMs
// over gathered rows (m97-style 128x128 tile, global_load_lds staging).
// Weights are converted+transposed to bf16 [N][K] in workspace each call.

#define D_MODEL 1024
#define D_FF    4096
#define NEXP    8
#define NTOK    8192
#define BM      128
#define BN      128
#define BK      32
#define MAXTILES 72

typedef __attribute__((ext_vector_type(8))) short bf16x8;
typedef __attribute__((ext_vector_type(4))) float f32x4;

// ---- workspace layout (bytes). total ~220 MB ----
#define OFF_META 0u                    // ints: [0..7] counts, [8..16] offsets, [17..24] fill, [25] ntiles, [32..103] tileE, [112..183] tileM
#define OFF_TOPI 4096u
#define OFF_PERM (4096u + 32768u)
#define OFF_XG   131072u                               // (8192+128)*1024*2  = 17039360
#define OFF_H    17170432u                             // (8192+128)*4096*2  = 68157440
#define OFF_W1T  85327872u                             // 8*4096*1024*2      = 67108864
#define OFF_W2T  152436736u                            // 8*1024*4096*2      = 67108864
// end ~219.5 MB

__device__ __forceinline__ unsigned short f2bf(float f) {
  unsigned int u = __builtin_bit_cast(unsigned int, f);
  unsigned int r = (u + 0x7FFFu + ((u >> 16) & 1u)) >> 16;
  return (unsigned short)r;
}

typedef const __attribute__((address_space(1))) unsigned int* gas_u32;
typedef __attribute__((address_space(3))) unsigned int* las_u32;

__device__ __forceinline__ void gload16(const void* g, void* l) {
  __builtin_amdgcn_global_load_lds((gas_u32)g, (las_u32)l, 16, 0, 0);
}

// ---------------- gating: one wave per token, fp64 accumulate ----------------
__global__ __launch_bounds__(256) void gate_kernel(const float* __restrict__ x,
    const float* __restrict__ gw, const float* __restrict__ gb,
    const float* __restrict__ eb, int* __restrict__ meta, int* __restrict__ topi) {
  int wid = threadIdx.x >> 6, lane = threadIdx.x & 63;
  int t = blockIdx.x * 4 + wid;
  const float* xr = x + (size_t)t * D_MODEL;
  double p[NEXP];
#pragma unroll
  for (int e = 0; e < NEXP; ++e) p[e] = 0.0;
#pragma unroll
  for (int j = 0; j < D_MODEL / 64; ++j) {
    int c = lane + j * 64;
    double xv = (double)xr[c];
#pragma unroll
    for (int e = 0; e < NEXP; ++e) p[e] += xv * (double)gw[e * D_MODEL + c];
  }
#pragma unroll
  for (int e = 0; e < NEXP; ++e) {
    for (int off = 32; off; off >>= 1) p[e] += __shfl_xor(p[e], off, 64);
  }
  if (lane == 0) {
    double best = -1e300; int bi = 0;
#pragma unroll
    for (int e = 0; e < NEXP; ++e) {
      double v = p[e] + (double)gb[e] + (double)eb[e];
      if (v > best) { best = v; bi = e; }   // strict > keeps first max (np.argmax)
    }
    topi[t] = bi;
    atomicAdd(meta + bi, 1);
  }
}

__global__ void init_kernel(int* meta) {
  if (threadIdx.x < 8) meta[threadIdx.x] = 0;
}

__global__ void scan_kernel(int* meta) {
  int* counts = meta; int* offs = meta + 8; int* fill = meta + 17;
  int* tileE = meta + 32; int* tileM = meta + 112;
  offs[0] = 0;
  int nt = 0;
  for (int e = 0; e < NEXP; ++e) {
    offs[e + 1] = offs[e] + counts[e];
    fill[e] = 0;
    int ntile = (counts[e] + BM - 1) / BM;
    for (int j = 0; j < ntile; ++j) { tileE[nt] = e; tileM[nt] = j; ++nt; }
  }
  meta[25] = nt;
}

// -------- scatter tokens into per-expert contiguous rows, f32 -> bf16 --------
__global__ __launch_bounds__(256) void scatter_kernel(const float* __restrict__ x,
    const int* __restrict__ topi, int* __restrict__ meta, int* __restrict__ perm,
    unsigned short* __restrict__ xg) {
  __shared__ int spos;
  int t = blockIdx.x;
  if (threadIdx.x == 0) {
    int e = topi[t];
    int p = meta[8 + e] + atomicAdd(meta + 17 + e, 1);
    perm[p] = t;
    spos = p;
  }
  __syncthreads();
  int pos = spos;
  const float* xr = x + (size_t)t * D_MODEL;
  unsigned short* orow = xg + (size_t)pos * D_MODEL;
#pragma unroll
  for (int j = 0; j < 4; ++j) {
    int c = threadIdx.x + j * 256;
    orow[c] = f2bf(xr[c]);
  }
}

// ---- weight convert + transpose: in [E][R][C] f32 -> out [E][C][R] bf16 ----
__global__ __launch_bounds__(256) void transconv_kernel(const float* __restrict__ in,
    unsigned short* __restrict__ out, int R, int C) {
  __shared__ float tile[32][33];
  int e = blockIdx.z;
  const float* src = in + (size_t)e * R * C;
  unsigned short* dst = out + (size_t)e * R * C;
  int c0 = blockIdx.x * 32, r0 = blockIdx.y * 32;
  int tx = threadIdx.x, ty = threadIdx.y;
#pragma unroll
  for (int i = 0; i < 4; ++i)
    tile[ty + i * 8][tx] = src[(size_t)(r0 + ty + i * 8) * C + c0 + tx];
  __syncthreads();
#pragma unroll
  for (int i = 0; i < 4; ++i)
    dst[(size_t)(c0 + ty + i * 8) * R + r0 + tx] = f2bf(tile[tx][ty + i * 8]);
}

// ------------------- m97-style gathered GEMM (bf16 MFMA) -------------------
// A: [rows][KDIM] bf16 row-major (gathered). Bt: [E][NDIM][KDIM] bf16.
// FFN1: h = relu(A @ B + b1) -> bf16.  FFN2: out[perm[row]] = A @ B + b2 (f32).
template<int KDIM, int NDIM, bool FFN1>
__global__ __launch_bounds__(256) void gemm_moe(
    const unsigned short* __restrict__ A,
    const unsigned short* __restrict__ Bt,
    const float* __restrict__ bias,
    const int* __restrict__ meta,
    const int* __restrict__ perm,
    unsigned short* __restrict__ Hout,
    float* __restrict__ Out) {
  int nt = meta[25];
  if ((int)blockIdx.x >= nt) return;
  int e = meta[32 + blockIdx.x];
  int lm = meta[112 + blockIdx.x];
  int off = meta[8 + e];
  int cnt = meta[8 + e + 1] - off;
  int rowsValid = cnt - lm * BM;
  int m0 = off + lm * BM;

  __shared__ unsigned short As[BM * BK];
  __shared__ unsigned short Bs[BN * BK];

  int tid = threadIdx.x;
  int lane = tid & 63, wid = tid >> 6;
  int waveM = wid >> 1, waveN = wid & 1;
  int lr = lane & 15, lg = lane >> 4;

  const char* aBase = (const char*)(A + (size_t)m0 * KDIM);
  const char* bBase = (const char*)(Bt + (size_t)e * NDIM * KDIM + (size_t)(blockIdx.y * BN) * KDIM);
  const int strideK = KDIM * 2;  // row stride bytes

  f32x4 acc[4][4];
#pragma unroll
  for (int i = 0; i < 4; ++i)
#pragma unroll
    for (int j = 0; j < 4; ++j) acc[i][j] = (f32x4){0.f, 0.f, 0.f, 0.f};

  const int o0 = tid * 16, o1 = tid * 16 + 4096;    // byte offsets into 8KB tile
  const int r0 = o0 >> 6, c0 = o0 & 63, r1 = o1 >> 6, c1 = o1 & 63;

  for (int it = 0; it < KDIM / BK; ++it) {
    const char* ak = aBase + it * 64;
    const char* bk = bBase + it * 64;
    gload16(ak + (size_t)r0 * strideK + c0, (char*)As + o0);
    gload16(ak + (size_t)r1 * strideK + c1, (char*)As + o1);
    gload16(bk + (size_t)r0 * strideK + c0, (char*)Bs + o0);
    gload16(bk + (size_t)r1 * strideK + c1, (char*)Bs + o1);
    __syncthreads();
    bf16x8 a[4], b[4];
#pragma unroll
    for (int mf = 0; mf < 4; ++mf)
      a[mf] = *(const bf16x8*)(As + (waveM * 64 + mf * 16 + lr) * BK + lg * 8);
#pragma unroll
    for (int nf = 0; nf < 4; ++nf)
      b[nf] = *(const bf16x8*)(Bs + (waveN * 64 + nf * 16 + lr) * BK + lg * 8);
#pragma unroll
    for (int mf = 0; mf < 4; ++mf)
#pragma unroll
      for (int nf = 0; nf < 4; ++nf)
        acc[mf][nf] = __builtin_amdgcn_mfma_f32_16x16x32_bf16(a[mf], b[nf], acc[mf][nf], 0, 0, 0);
    __syncthreads();
  }

#pragma unroll
  for (int mf = 0; mf < 4; ++mf) {
#pragma unroll
    for (int r = 0; r < 4; ++r) {
      int rowt = waveM * 64 + mf * 16 + lg * 4 + r;   // C/D: row=(lane>>4)*4+reg
      if (rowt >= rowsValid) continue;
      if (FFN1) {
        size_t rowOff = (size_t)(m0 + rowt) * NDIM;
#pragma unroll
        for (int nf = 0; nf < 4; ++nf) {
          int col = blockIdx.y * BN + waveN * 64 + nf * 16 + lr;  // col=lane&15
          float v = acc[mf][nf][r] + bias[e * NDIM + col];
          v = fmaxf(v, 0.f);
          Hout[rowOff + col] = f2bf(v);
        }
      } else {
        int tok = perm[m0 + rowt];
        size_t rowOff = (size_t)tok * NDIM;
#pragma unroll
        for (int nf = 0; nf < 4; ++nf) {
          int col = blockIdx.y * BN + waveN * 64 + nf * 16 + lr;
          Out[rowOff + col] = acc[mf][nf][r] + bias[e * NDIM + col];
        }
      }
    }
  }
}

extern "C" void kernel_launch(void* const* d_in, const int* in_sizes, int n_in,
                              void* d_out, int out_size, void* d_ws, size_t ws_size,
                              hipStream_t stream) {
  const float* x  = (const float*)d_in[0];
  const float* gw = (const float*)d_in[1];
  const float* gb = (const float*)d_in[2];
  const float* eb = (const float*)d_in[3];
  const float* w1 = (const float*)d_in[4];
  const float* b1 = (const float*)d_in[5];
  const float* w2 = (const float*)d_in[6];
  const float* b2 = (const float*)d_in[7];
  float* out = (float*)d_out;

  char* ws = (char*)d_ws;
  int* meta = (int*)(ws + OFF_META);
  int* topi = (int*)(ws + OFF_TOPI);
  int* perm = (int*)(ws + OFF_PERM);
  unsigned short* xg  = (unsigned short*)(ws + OFF_XG);
  unsigned short* h   = (unsigned short*)(ws + OFF_H);
  unsigned short* w1t = (unsigned short*)(ws + OFF_W1T);
  unsigned short* w2t = (unsigned short*)(ws + OFF_W2T);

  hipLaunchKernelGGL(init_kernel, dim3(1), dim3(64), 0, stream, meta);
  hipLaunchKernelGGL(gate_kernel, dim3(NTOK / 4), dim3(256), 0, stream, x, gw, gb, eb, meta, topi);
  hipLaunchKernelGGL(scan_kernel, dim3(1), dim3(1), 0, stream, meta);
  hipLaunchKernelGGL(scatter_kernel, dim3(NTOK), dim3(256), 0, stream, x, topi, meta, perm, xg);
  // w1: [E][1024][4096] -> w1t [E][4096][1024]
  hipLaunchKernelGGL(transconv_kernel, dim3(D_FF / 32, D_MODEL / 32, NEXP), dim3(32, 8), 0, stream,
                     w1, w1t, D_MODEL, D_FF);
  // w2: [E][4096][1024] -> w2t [E][1024][4096]
  hipLaunchKernelGGL(transconv_kernel, dim3(D_MODEL / 32, D_FF / 32, NEXP), dim3(32, 8), 0, stream,
                     w2, w2t, D_FF, D_MODEL);
  hipLaunchKernelGGL((gemm_moe<D_MODEL, D_FF, true>), dim3(MAXTILES, D_FF / BN), dim3(256), 0, stream,
                     xg, w1t, b1, meta, perm, h, nullptr);
  hipLaunchKernelGGL((gemm_moe<D_FF, D_MODEL, false>), dim3(MAXTILES, D_MODEL / BN), dim3(256), 0, stream,
                     h, w2t, b2, meta, perm, nullptr, out);
}

// Round 2
// 511.411 us; speedup vs baseline: 1.0506x; 1.0506x over previous
//
#include <hip/hip_runtime.h>
#include <hip/hip_bf16.h>
#include <stdint.h>

// MoE FFN, top-1 routing. x:[4,2048,1024] f32, 8 experts, 1024->4096->1024.
// fp64 gate+argmax -> bucket tokens -> bf16 MFMA GEMMs over gathered rows.
// R2: fast 64x64 transconv, FFN2 8-wave blocks, XCD-swizzled tile order.

#define D_MODEL 1024
#define D_FF    4096
#define NEXP    8
#define NTOK    8192
#define BM      128
#define BK      32
#define MAXTILES 72

typedef __attribute__((ext_vector_type(8))) short bf16x8;
typedef __attribute__((ext_vector_type(8))) unsigned short u16x8;
typedef __attribute__((ext_vector_type(4))) float f32x4;

// ---- workspace layout (bytes) ----
#define OFF_META 0u
#define OFF_TOPI 4096u
#define OFF_PERM (4096u + 32768u)
#define OFF_XG   131072u                               // 8320*1024*2
#define OFF_H    17170432u                             // 8320*4096*2
#define OFF_W1T  85327872u                             // 8*4096*1024*2
#define OFF_W2T  152436736u                            // 8*1024*4096*2

__device__ __forceinline__ unsigned short f2bf(float f) {
  unsigned int u = __builtin_bit_cast(unsigned int, f);
  unsigned int r = (u + 0x7FFFu + ((u >> 16) & 1u)) >> 16;
  return (unsigned short)r;
}

typedef const __attribute__((address_space(1))) unsigned int* gas_u32;
typedef __attribute__((address_space(3))) unsigned int* las_u32;

__device__ __forceinline__ void gload16(const void* g, void* l) {
  __builtin_amdgcn_global_load_lds((gas_u32)g, (las_u32)l, 16, 0, 0);
}

// bijective XCD swizzle + n-grouped decode: consecutive wid within an XCD
// chunk cycle GN n-panels (L2-resident) while marching m-tiles.
__device__ __forceinline__ int xcd_swz(int orig, int nwg) {
  int q = nwg >> 3, r = nwg & 7;
  int xcd = orig & 7, lid = orig >> 3;
  return (xcd < r ? xcd * (q + 1) : r * (q + 1) + (xcd - r) * q) + lid;
}

// ---------------- gating: one wave per token, fp64 accumulate ----------------
__global__ __launch_bounds__(256) void gate_kernel(const float* __restrict__ x,
    const float* __restrict__ gw, const float* __restrict__ gb,
    const float* __restrict__ eb, int* __restrict__ meta, int* __restrict__ topi) {
  int wid = threadIdx.x >> 6, lane = threadIdx.x & 63;
  int t = blockIdx.x * 4 + wid;
  const float* xr = x + (size_t)t * D_MODEL;
  double p[NEXP];
#pragma unroll
  for (int e = 0; e < NEXP; ++e) p[e] = 0.0;
#pragma unroll
  for (int j = 0; j < D_MODEL / 64; ++j) {
    int c = lane + j * 64;
    double xv = (double)xr[c];
#pragma unroll
    for (int e = 0; e < NEXP; ++e) p[e] += xv * (double)gw[e * D_MODEL + c];
  }
#pragma unroll
  for (int e = 0; e < NEXP; ++e) {
    for (int off = 32; off; off >>= 1) p[e] += __shfl_xor(p[e], off, 64);
  }
  if (lane == 0) {
    double best = -1e300; int bi = 0;
#pragma unroll
    for (int e = 0; e < NEXP; ++e) {
      double v = p[e] + (double)gb[e] + (double)eb[e];
      if (v > best) { best = v; bi = e; }
    }
    topi[t] = bi;
    atomicAdd(meta + bi, 1);
  }
}

__global__ void init_kernel(int* meta) {
  if (threadIdx.x < 8) meta[threadIdx.x] = 0;
}

__global__ void scan_kernel(int* meta) {
  int* counts = meta; int* offs = meta + 8; int* fill = meta + 17;
  int* tileE = meta + 32; int* tileM = meta + 112;
  offs[0] = 0;
  int nt = 0;
  for (int e = 0; e < NEXP; ++e) {
    offs[e + 1] = offs[e] + counts[e];
    fill[e] = 0;
    int ntile = (counts[e] + BM - 1) / BM;
    for (int j = 0; j < ntile; ++j) { tileE[nt] = e; tileM[nt] = j; ++nt; }
  }
  meta[25] = nt;
}

// -------- scatter tokens into per-expert contiguous rows, f32 -> bf16 --------
__global__ __launch_bounds__(256) void scatter_kernel(const float* __restrict__ x,
    const int* __restrict__ topi, int* __restrict__ meta, int* __restrict__ perm,
    unsigned short* __restrict__ xg) {
  __shared__ int spos;
  int t = blockIdx.x;
  if (threadIdx.x == 0) {
    int e = topi[t];
    int p = meta[8 + e] + atomicAdd(meta + 17 + e, 1);
    perm[p] = t;
    spos = p;
  }
  __syncthreads();
  int pos = spos;
  const float* xr = x + (size_t)t * D_MODEL;
  unsigned short* orow = xg + (size_t)pos * D_MODEL;
#pragma unroll
  for (int j = 0; j < 4; ++j) {
    int c = threadIdx.x + j * 256;
    orow[c] = f2bf(xr[c]);
  }
}

// ---- weight convert+transpose v2: [E][R][C] f32 -> [E][C][R] bf16 ----
// 64x64 tile. float4 reads, bf16x8 (16B) writes, LDS pad 65 (2-way = free).
__global__ __launch_bounds__(256) void transconv2(const float* __restrict__ in,
    unsigned short* __restrict__ out, int R, int C) {
  __shared__ float tile[64][65];
  int e = blockIdx.z;
  const float* src = in + (size_t)e * R * C;
  unsigned short* dst = out + (size_t)e * R * C;
  int c0 = blockIdx.x * 64, r0 = blockIdx.y * 64;
  int tid = threadIdx.x;
  int rr = tid >> 4, cc4 = (tid & 15) * 4;
#pragma unroll
  for (int i = 0; i < 4; ++i) {
    f32x4 v = *(const f32x4*)(src + (size_t)(r0 + rr + i * 16) * C + c0 + cc4);
#pragma unroll
    for (int j = 0; j < 4; ++j) tile[rr + i * 16][cc4 + j] = v[j];
  }
  __syncthreads();
  int cc = tid >> 3, rr8 = (tid & 7) * 8;
#pragma unroll
  for (int i = 0; i < 2; ++i) {
    int c = cc + i * 32;
    u16x8 u;
#pragma unroll
    for (int j = 0; j < 8; ++j) u[j] = f2bf(tile[rr8 + j][c]);
    *(u16x8*)(dst + (size_t)(c0 + c) * R + r0 + rr8) = u;
  }
}

// ------------------- FFN1: 128x128 tile, 256 thr, m97 structure -------------
__global__ __launch_bounds__(256) void gemm_ffn1(
    const unsigned short* __restrict__ A, const unsigned short* __restrict__ Bt,
    const float* __restrict__ bias, const int* __restrict__ meta,
    unsigned short* __restrict__ H) {
  const int NB = D_FF / 128;   // 32 n-panels
  const int GN = 8;
  int ntiles = meta[25];
  int nwg = ntiles * NB;
  int orig = blockIdx.x;
  if (orig >= nwg) return;
  int wid = xcd_swz(orig, nwg);
  int per = ntiles * GN;
  int sc = wid / per, rem = wid % per;
  int t = rem / GN, nb = sc * GN + rem % GN;

  int e = meta[32 + t];
  int lm = meta[112 + t];
  int off = meta[8 + e];
  int rowsValid = meta[8 + e + 1] - off - lm * BM;
  int m0 = off + lm * BM;

  __shared__ unsigned short As[BM * BK];
  __shared__ unsigned short Bs[BM * BK];

  int tid = threadIdx.x;
  int lane = tid & 63, wv = tid >> 6;
  int waveM = wv >> 1, waveN = wv & 1;
  int lr = lane & 15, lg = lane >> 4;

  const char* aBase = (const char*)(A + (size_t)m0 * D_MODEL);
  const char* bBase = (const char*)(Bt + (size_t)e * D_FF * D_MODEL + (size_t)(nb * 128) * D_MODEL);
  const int strideK = D_MODEL * 2;

  f32x4 acc[4][4];
#pragma unroll
  for (int i = 0; i < 4; ++i)
#pragma unroll
    for (int j = 0; j < 4; ++j) acc[i][j] = (f32x4){0.f, 0.f, 0.f, 0.f};

  const int o0 = tid * 16, o1 = tid * 16 + 4096;
  const int r0 = o0 >> 6, c0 = o0 & 63, r1 = o1 >> 6, c1 = o1 & 63;

  for (int it = 0; it < D_MODEL / BK; ++it) {
    const char* ak = aBase + it * 64;
    const char* bk = bBase + it * 64;
    gload16(ak + (size_t)r0 * strideK + c0, (char*)As + o0);
    gload16(ak + (size_t)r1 * strideK + c1, (char*)As + o1);
    gload16(bk + (size_t)r0 * strideK + c0, (char*)Bs + o0);
    gload16(bk + (size_t)r1 * strideK + c1, (char*)Bs + o1);
    __syncthreads();
    bf16x8 a[4], b[4];
#pragma unroll
    for (int mf = 0; mf < 4; ++mf)
      a[mf] = *(const bf16x8*)(As + (waveM * 64 + mf * 16 + lr) * BK + lg * 8);
#pragma unroll
    for (int nf = 0; nf < 4; ++nf)
      b[nf] = *(const bf16x8*)(Bs + (waveN * 64 + nf * 16 + lr) * BK + lg * 8);
#pragma unroll
    for (int mf = 0; mf < 4; ++mf)
#pragma unroll
      for (int nf = 0; nf < 4; ++nf)
        acc[mf][nf] = __builtin_amdgcn_mfma_f32_16x16x32_bf16(a[mf], b[nf], acc[mf][nf], 0, 0, 0);
    __syncthreads();
  }

#pragma unroll
  for (int mf = 0; mf < 4; ++mf) {
#pragma unroll
    for (int rg = 0; rg < 4; ++rg) {
      int rowt = waveM * 64 + mf * 16 + lg * 4 + rg;
      if (rowt >= rowsValid) continue;
      size_t rowOff = (size_t)(m0 + rowt) * D_FF;
#pragma unroll
      for (int nf = 0; nf < 4; ++nf) {
        int col = nb * 128 + waveN * 64 + nf * 16 + lr;
        float v = acc[mf][nf][rg] + bias[e * D_FF + col];
        H[rowOff + col] = f2bf(fmaxf(v, 0.f));
      }
    }
  }
}

// ---------- FFN2: 128x128 tile, 512 thr (8 waves 2Mx4N), K=4096 -------------
__global__ __launch_bounds__(512) void gemm_ffn2(
    const unsigned short* __restrict__ A, const unsigned short* __restrict__ Bt,
    const float* __restrict__ bias, const int* __restrict__ meta,
    const int* __restrict__ perm, float* __restrict__ Out) {
  const int NB = D_MODEL / 128;  // 8 n-panels
  const int GN = 4;
  int ntiles = meta[25];
  int nwg = ntiles * NB;
  int orig = blockIdx.x;
  if (orig >= nwg) return;
  int wid = xcd_swz(orig, nwg);
  int per = ntiles * GN;
  int sc = wid / per, rem = wid % per;
  int t = rem / GN, nb = sc * GN + rem % GN;

  int e = meta[32 + t];
  int lm = meta[112 + t];
  int off = meta[8 + e];
  int rowsValid = meta[8 + e + 1] - off - lm * BM;
  int m0 = off + lm * BM;

  __shared__ unsigned short As[BM * BK];
  __shared__ unsigned short Bs[BM * BK];

  int tid = threadIdx.x;
  int lane = tid & 63, wv = tid >> 6;        // 8 waves
  int waveM = wv >> 2, waveN = wv & 3;       // 2 x 4
  int lr = lane & 15, lg = lane >> 4;

  const char* aBase = (const char*)(A + (size_t)m0 * D_FF);
  const char* bBase = (const char*)(Bt + (size_t)e * D_MODEL * D_FF + (size_t)(nb * 128) * D_FF);
  const int strideK = D_FF * 2;

  f32x4 acc[4][2];
#pragma unroll
  for (int i = 0; i < 4; ++i)
#pragma unroll
    for (int j = 0; j < 2; ++j) acc[i][j] = (f32x4){0.f, 0.f, 0.f, 0.f};

  const int o0 = tid * 16;                   // 512 thr x 16B = full 8KB tile
  const int r0 = o0 >> 6, c0 = o0 & 63;

  for (int it = 0; it < D_FF / BK; ++it) {
    const char* ak = aBase + it * 64;
    const char* bk = bBase + it * 64;
    gload16(ak + (size_t)r0 * strideK + c0, (char*)As + o0);
    gload16(bk + (size_t)r0 * strideK + c0, (char*)Bs + o0);
    __syncthreads();
    bf16x8 a[4], b[2];
#pragma unroll
    for (int mf = 0; mf < 4; ++mf)
      a[mf] = *(const bf16x8*)(As + (waveM * 64 + mf * 16 + lr) * BK + lg * 8);
#pragma unroll
    for (int nf = 0; nf < 2; ++nf)
      b[nf] = *(const bf16x8*)(Bs + (waveN * 32 + nf * 16 + lr) * BK + lg * 8);
#pragma unroll
    for (int mf = 0; mf < 4; ++mf)
#pragma unroll
      for (int nf = 0; nf < 2; ++nf)
        acc[mf][nf] = __builtin_amdgcn_mfma_f32_16x16x32_bf16(a[mf], b[nf], acc[mf][nf], 0, 0, 0);
    __syncthreads();
  }

#pragma unroll
  for (int mf = 0; mf < 4; ++mf) {
#pragma unroll
    for (int rg = 0; rg < 4; ++rg) {
      int rowt = waveM * 64 + mf * 16 + lg * 4 + rg;
      if (rowt >= rowsValid) continue;
      int tok = perm[m0 + rowt];
      size_t rowOff = (size_t)tok * D_MODEL;
#pragma unroll
      for (int nf = 0; nf < 2; ++nf) {
        int col = nb * 128 + waveN * 32 + nf * 16 + lr;
        Out[rowOff + col] = acc[mf][nf][rg] + bias[e * D_MODEL + col];
      }
    }
  }
}

extern "C" void kernel_launch(void* const* d_in, const int* in_sizes, int n_in,
                              void* d_out, int out_size, void* d_ws, size_t ws_size,
                              hipStream_t stream) {
  const float* x  = (const float*)d_in[0];
  const float* gw = (const float*)d_in[1];
  const float* gb = (const float*)d_in[2];
  const float* eb = (const float*)d_in[3];
  const float* w1 = (const float*)d_in[4];
  const float* b1 = (const float*)d_in[5];
  const float* w2 = (const float*)d_in[6];
  const float* b2 = (const float*)d_in[7];
  float* out = (float*)d_out;

  char* ws = (char*)d_ws;
  int* meta = (int*)(ws + OFF_META);
  int* topi = (int*)(ws + OFF_TOPI);
  int* perm = (int*)(ws + OFF_PERM);
  unsigned short* xg  = (unsigned short*)(ws + OFF_XG);
  unsigned short* h   = (unsigned short*)(ws + OFF_H);
  unsigned short* w1t = (unsigned short*)(ws + OFF_W1T);
  unsigned short* w2t = (unsigned short*)(ws + OFF_W2T);

  hipLaunchKernelGGL(init_kernel, dim3(1), dim3(64), 0, stream, meta);
  hipLaunchKernelGGL(gate_kernel, dim3(NTOK / 4), dim3(256), 0, stream, x, gw, gb, eb, meta, topi);
  hipLaunchKernelGGL(scan_kernel, dim3(1), dim3(1), 0, stream, meta);
  hipLaunchKernelGGL(scatter_kernel, dim3(NTOK), dim3(256), 0, stream, x, topi, meta, perm, xg);
  // w1: [E][1024][4096] -> w1t [E][4096][1024]
  hipLaunchKernelGGL(transconv2, dim3(D_FF / 64, D_MODEL / 64, NEXP), dim3(256), 0, stream,
                     w1, w1t, D_MODEL, D_FF);
  // w2: [E][4096][1024] -> w2t [E][1024][4096]
  hipLaunchKernelGGL(transconv2, dim3(D_MODEL / 64, D_FF / 64, NEXP), dim3(256), 0, stream,
                     w2, w2t, D_FF, D_MODEL);
  hipLaunchKernelGGL(gemm_ffn1, dim3(MAXTILES * (D_FF / 128)), dim3(256), 0, stream,
                     xg, w1t, b1, meta, h);
  hipLaunchKernelGGL(gemm_ffn2, dim3(MAXTILES * (D_MODEL / 128)), dim3(512), 0, stream,
                     h, w2t, b2, meta, perm, out);
}